// Round 20
// baseline (202.117 us; speedup 1.0000x reference)
//
#include <hip/hip_runtime.h>
#include <cstdint>

// Problem constants (fixed by the reference)
#define N_SEQ 4096
#define DMODEL 1024

#define BM 128
#define BN 128
#define BN2 64
#define UNITE 4096   // one 64x64 f16 unit (8 KiB)

typedef __bf16 bf16_t;
typedef _Float16 f16_t;
typedef f16_t f16x8 __attribute__((ext_vector_type(8)));
typedef f16_t f16x4 __attribute__((ext_vector_type(4)));
typedef float f32x4 __attribute__((ext_vector_type(4)));

typedef __attribute__((address_space(1))) void* as1ptr;
typedef __attribute__((address_space(3))) void* as3ptr;

__device__ __forceinline__ void gload16(const void* g, void* l) {
  __builtin_amdgcn_global_load_lds((as1ptr)(uintptr_t)g, (as3ptr)(uintptr_t)l,
                                   16, 0, 0);
}

#define SBAR() asm volatile("s_barrier" ::: "memory")
#define WAITLGKM(n)                                              \
  do {                                                           \
    asm volatile("s_waitcnt lgkmcnt(" #n ")" ::: "memory");      \
    __builtin_amdgcn_sched_barrier(0);                           \
  } while (0)
#define WAITVM(n) asm volatile("s_waitcnt vmcnt(" #n ")" ::: "memory")

// ================= fused QKV projection (z = 0:Q, 1:K, 2:V) =================
// All-fp16, BK=64 swizzled units.  LDS 48 KiB -> 3 blocks/CU.
// z=0 (Q, 2-pass): qp = (qh+ql)@wq^T + b -> fp16 QPh
// z=1 (K, 2-pass): kp = (kh+kl)@wk^T + b -> fp16 KPh
// z=2 (V, 1-pass): vp = vh@wv^T + b      -> fp16 transposed VPt
__global__ __launch_bounds__(256)
void qkv_proj(const f16_t* __restrict__ qh, const f16_t* __restrict__ ql,
              const f16_t* __restrict__ wq, const float* __restrict__ wq_b,
              const f16_t* __restrict__ kh, const f16_t* __restrict__ kl,
              const f16_t* __restrict__ wk, const float* __restrict__ wk_b,
              const f16_t* __restrict__ vh, const f16_t* __restrict__ wv,
              const float* __restrict__ wv_b,
              f16_t* __restrict__ QPh, f16_t* __restrict__ KPh,
              f16_t* __restrict__ VPt)
{
  __shared__ __align__(16) f16_t lds[6 * UNITE];   // 48 KiB

  const int z = blockIdx.z;
  const f16_t *A0, *A1 = nullptr, *B0;
  const float* bias;
  if (z == 0)      { A0 = qh; A1 = ql; B0 = wq; bias = wq_b; }
  else if (z == 1) { A0 = kh; A1 = kl; B0 = wk; bias = wk_b; }
  else             { A0 = vh;          B0 = wv; bias = wv_b; }
  const bool twop = (z < 2);

  const int M = N_SEQ, Nc = DMODEL, K = DMODEL;
  const int t = threadIdx.x;
  const int lane = t & 63;
  const int wave = t >> 6;
  const int wm = wave >> 1;
  const int wn = wave & 1;

  const int gx = gridDim.x;                       // 8
  const int nwg = gx * gridDim.y;                 // 256
  const int flat = blockIdx.y * gx + blockIdx.x;
  const int swz = (flat & 7) * (nwg >> 3) + (flat >> 3);
  const int row0 = (swz / gx) * BM;
  const int col0 = (swz % gx) * BN;

  const int srw = t >> 3;                                // 0..31
  const int scol = 8 * ((t & 7) ^ ((t >> 3) & 7));       // pre-swizzled src
  const int sdst = t * 8;

  const int fr = lane & 15;
  const int kq = (lane >> 4) * 8;
  const int sw = (fr & 7) << 3;                          // read-side swizzle

  f32x4 acc[4][4] = {};

  for (int k0 = 0; k0 < K; k0 += 64) {
#pragma unroll
    for (int h = 0; h < 2; ++h) {
      const int r = h * 32 + srw;
      gload16(A0 + (size_t)(row0 + r) * K + k0 + scol,
              &lds[0 * UNITE + h * 2048 + sdst]);
      gload16(A0 + (size_t)(row0 + 64 + r) * K + k0 + scol,
              &lds[1 * UNITE + h * 2048 + sdst]);
      gload16(B0 + (size_t)(col0 + r) * K + k0 + scol,
              &lds[4 * UNITE + h * 2048 + sdst]);
      gload16(B0 + (size_t)(col0 + 64 + r) * K + k0 + scol,
              &lds[5 * UNITE + h * 2048 + sdst]);
      if (twop) {
        gload16(A1 + (size_t)(row0 + r) * K + k0 + scol,
                &lds[2 * UNITE + h * 2048 + sdst]);
        gload16(A1 + (size_t)(row0 + 64 + r) * K + k0 + scol,
                &lds[3 * UNITE + h * 2048 + sdst]);
      }
    }
    __syncthreads();

    f16x8 ah[4][2], al[4][2], bh[4][2];
#pragma unroll
    for (int m = 0; m < 4; ++m) {
      const int r = (m * 16 + fr) * 64;
#pragma unroll
      for (int ks = 0; ks < 2; ++ks) {
        const int c = (ks * 32 + kq) ^ sw;
        ah[m][ks] = *(const f16x8*)&lds[wm * UNITE + r + c];
        if (twop) al[m][ks] = *(const f16x8*)&lds[(2 + wm) * UNITE + r + c];
      }
    }
#pragma unroll
    for (int n = 0; n < 4; ++n) {
      const int r = (n * 16 + fr) * 64;
#pragma unroll
      for (int ks = 0; ks < 2; ++ks)
        bh[n][ks] = *(const f16x8*)&lds[(4 + wn) * UNITE + r +
                                        (((ks * 32 + kq)) ^ sw)];
    }

#pragma unroll
    for (int m = 0; m < 4; ++m)
#pragma unroll
      for (int n = 0; n < 4; ++n)
#pragma unroll
        for (int ks = 0; ks < 2; ++ks) {
          acc[m][n] = __builtin_amdgcn_mfma_f32_16x16x32_f16(
              ah[m][ks], bh[n][ks], acc[m][n], 0, 0, 0);
          if (twop)
            acc[m][n] = __builtin_amdgcn_mfma_f32_16x16x32_f16(
                al[m][ks], bh[n][ks], acc[m][n], 0, 0, 0);
        }
    __syncthreads();
  }

#pragma unroll
  for (int m = 0; m < 4; ++m) {
#pragma unroll
    for (int n = 0; n < 4; ++n) {
      const int grow0 = row0 + wm * 64 + m * 16 + (lane >> 4) * 4;
      const int gcol = col0 + wn * 64 + n * 16 + (lane & 15);
      const float bv = bias[gcol];
      if (z == 2) {
        f16x4 p;
#pragma unroll
        for (int r = 0; r < 4; ++r) p[r] = (f16_t)(acc[m][n][r] + bv);
        *(f16x4*)&VPt[(size_t)gcol * M + grow0] = p;
      } else {
        f16_t* out = (z == 0) ? QPh : KPh;
#pragma unroll
        for (int r = 0; r < 4; ++r)
          out[(size_t)(grow0 + r) * Nc + gcol] = (f16_t)(acc[m][n][r] + bv);
      }
    }
  }
}

// ====== pipelined fp16 GEMM, 128x64 tile, BK=64 double-buffered ======
template <int OUT_F32>
__global__ __launch_bounds__(256)
void gemm_f16p(const f16_t* __restrict__ A, const f16_t* __restrict__ B,
               const float* __restrict__ bias,
               f16_t* __restrict__ Cf16, float* __restrict__ Cf32,
               int M, int Nc, int K)
{
  __shared__ __align__(16) f16_t lds[2 * 3 * UNITE];   // 48 KiB

  const int gx = gridDim.x;
  const int nwg = gx * gridDim.y;
  const int flat = blockIdx.y * gx + blockIdx.x;
  const int swz = (flat & 7) * (nwg >> 3) + (flat >> 3);
  const int bx = swz % gx;
  const int by = swz / gx;

  const int t = threadIdx.x;
  const int lane = t & 63;
  const int wave = t >> 6;
  const int wm = wave >> 1;
  const int wn = wave & 1;
  const int row0 = by * BM;
  const int col0 = bx * BN2;

  const int srw = t >> 3;
  const int scol = 8 * ((t & 7) ^ ((t >> 3) & 7));
  const int sdst = t * 8;

  const int fr = lane & 15;
  const int kq = (lane >> 4) * 8;
  const int sw = (fr & 7) << 3;

  auto stage = [&](int buf, int kt) {
    const int k0 = kt << 6;
#pragma unroll
    for (int h = 0; h < 2; ++h) {
      const int r = h * 32 + srw;
      gload16(A + (size_t)(row0 + r) * K + k0 + scol,
              &lds[(buf * 3 + 0) * UNITE + h * 2048 + sdst]);
      gload16(A + (size_t)(row0 + 64 + r) * K + k0 + scol,
              &lds[(buf * 3 + 1) * UNITE + h * 2048 + sdst]);
      gload16(B + (size_t)(col0 + r) * K + k0 + scol,
              &lds[(buf * 3 + 2) * UNITE + h * 2048 + sdst]);
    }
  };

  f32x4 acc[4][2] = {};
  const int NT = K >> 6;

  stage(0, 0);
  stage(1, 1);
  WAITVM(6);
  SBAR();

  for (int kt = 0; kt < NT; ++kt) {
    const int p = kt & 1;
    const f16_t* Ab = &lds[(p * 3 + wm) * UNITE];
    const f16_t* Bb = &lds[(p * 3 + 2) * UNITE];

    f16x8 ah[4][2], bh[2][2];
#pragma unroll
    for (int m = 0; m < 2; ++m)
#pragma unroll
      for (int ks = 0; ks < 2; ++ks)
        ah[m][ks] = *(const f16x8*)&Ab[(m * 16 + fr) * 64 +
                                       ((ks * 32 + kq) ^ sw)];
#pragma unroll
    for (int n = 0; n < 2; ++n)
#pragma unroll
      for (int ks = 0; ks < 2; ++ks)
        bh[n][ks] = *(const f16x8*)&Bb[(wn * 32 + n * 16 + fr) * 64 +
                                       ((ks * 32 + kq) ^ sw)];
#pragma unroll
    for (int m = 2; m < 4; ++m)
#pragma unroll
      for (int ks = 0; ks < 2; ++ks)
        ah[m][ks] = *(const f16x8*)&Ab[(m * 16 + fr) * 64 +
                                       ((ks * 32 + kq) ^ sw)];

    WAITLGKM(4);
#pragma unroll
    for (int m = 0; m < 2; ++m)
#pragma unroll
      for (int n = 0; n < 2; ++n)
#pragma unroll
        for (int ks = 0; ks < 2; ++ks)
          acc[m][n] = __builtin_amdgcn_mfma_f32_16x16x32_f16(
              ah[m][ks], bh[n][ks], acc[m][n], 0, 0, 0);
    WAITLGKM(0);
#pragma unroll
    for (int m = 2; m < 4; ++m)
#pragma unroll
      for (int n = 0; n < 2; ++n)
#pragma unroll
        for (int ks = 0; ks < 2; ++ks)
          acc[m][n] = __builtin_amdgcn_mfma_f32_16x16x32_f16(
              ah[m][ks], bh[n][ks], acc[m][n], 0, 0, 0);

    SBAR();
    if (kt + 2 < NT) {
      stage(p, kt + 2);
      WAITVM(6);
    } else if (kt + 1 < NT) {
      WAITVM(0);
    }
    SBAR();
  }

#pragma unroll
  for (int m = 0; m < 4; ++m) {
#pragma unroll
    for (int n = 0; n < 2; ++n) {
      const int grow0 = row0 + wm * 64 + m * 16 + (lane >> 4) * 4;
      const int gcol = col0 + wn * 32 + n * 16 + (lane & 15);
#pragma unroll
      for (int r = 0; r < 4; ++r) {
        const size_t idx = (size_t)(grow0 + r) * Nc + gcol;
        if (OUT_F32) Cf32[idx] = acc[m][n][r] + bias[gcol];
        else         Cf16[idx] = (f16_t)acc[m][n][r];
      }
    }
  }
}

// ====== pipelined fp16 scores GEMM, 128x128 tile, BK=64 dbuf -> fp32 ======
__global__ __launch_bounds__(256)
void gemm_f16s(const f16_t* __restrict__ A, const f16_t* __restrict__ B,
               float* __restrict__ C, int M, int Nc, int K)
{
  __shared__ __align__(16) f16_t lds[2 * 4 * UNITE];   // 64 KiB

  const int gx = gridDim.x;
  const int nwg = gx * gridDim.y;
  const int flat = blockIdx.y * gx + blockIdx.x;
  const int swz = (flat & 7) * (nwg >> 3) + (flat >> 3);
  const int bx = swz % gx;
  const int by = swz / gx;

  const int t = threadIdx.x;
  const int lane = t & 63;
  const int wave = t >> 6;
  const int wm = wave >> 1;
  const int wn = wave & 1;
  const int row0 = by * BM;
  const int col0 = bx * BN;

  const int srw = t >> 3;
  const int scol = 8 * ((t & 7) ^ ((t >> 3) & 7));
  const int sdst = t * 8;

  const int fr = lane & 15;
  const int kq = (lane >> 4) * 8;
  const int sw = (fr & 7) << 3;

  auto stage = [&](int buf, int kt) {
    const int k0 = kt << 6;
#pragma unroll
    for (int h = 0; h < 2; ++h) {
      const int r = h * 32 + srw;
      gload16(A + (size_t)(row0 + r) * K + k0 + scol,
              &lds[(buf * 4 + 0) * UNITE + h * 2048 + sdst]);
      gload16(A + (size_t)(row0 + 64 + r) * K + k0 + scol,
              &lds[(buf * 4 + 1) * UNITE + h * 2048 + sdst]);
      gload16(B + (size_t)(col0 + r) * K + k0 + scol,
              &lds[(buf * 4 + 2) * UNITE + h * 2048 + sdst]);
      gload16(B + (size_t)(col0 + 64 + r) * K + k0 + scol,
              &lds[(buf * 4 + 3) * UNITE + h * 2048 + sdst]);
    }
  };

  f32x4 acc[4][4] = {};
  const int NT = K >> 6;   // 16

  stage(0, 0);
  stage(1, 1);
  WAITVM(8);
  SBAR();

  for (int kt = 0; kt < NT; ++kt) {
    const int p = kt & 1;
    const f16_t* Ab = &lds[(p * 4 + wm) * UNITE];
    const f16_t* Bb = &lds[(p * 4 + 2 + wn) * UNITE];

    f16x8 ah[4][2], bh[4][2];
#pragma unroll
    for (int m = 0; m < 4; ++m)
#pragma unroll
      for (int ks = 0; ks < 2; ++ks)
        ah[m][ks] = *(const f16x8*)&Ab[(m * 16 + fr) * 64 +
                                       ((ks * 32 + kq) ^ sw)];
#pragma unroll
    for (int n = 0; n < 2; ++n)
#pragma unroll
      for (int ks = 0; ks < 2; ++ks)
        bh[n][ks] = *(const f16x8*)&Bb[(n * 16 + fr) * 64 +
                                       ((ks * 32 + kq) ^ sw)];
#pragma unroll
    for (int n = 2; n < 4; ++n)
#pragma unroll
      for (int ks = 0; ks < 2; ++ks)
        bh[n][ks] = *(const f16x8*)&Bb[(n * 16 + fr) * 64 +
                                       ((ks * 32 + kq) ^ sw)];

    WAITLGKM(4);
#pragma unroll
    for (int m = 0; m < 4; ++m)
#pragma unroll
      for (int n = 0; n < 2; ++n)
#pragma unroll
        for (int ks = 0; ks < 2; ++ks)
          acc[m][n] = __builtin_amdgcn_mfma_f32_16x16x32_f16(
              ah[m][ks], bh[n][ks], acc[m][n], 0, 0, 0);
    WAITLGKM(0);
#pragma unroll
    for (int m = 0; m < 4; ++m)
#pragma unroll
      for (int n = 2; n < 4; ++n)
#pragma unroll
        for (int ks = 0; ks < 2; ++ks)
          acc[m][n] = __builtin_amdgcn_mfma_f32_16x16x32_f16(
              ah[m][ks], bh[n][ks], acc[m][n], 0, 0, 0);

    SBAR();
    if (kt + 2 < NT) {
      stage(p, kt + 2);
      WAITVM(8);
    } else if (kt + 1 < NT) {
      WAITVM(0);
    }
    SBAR();
  }

#pragma unroll
  for (int m = 0; m < 4; ++m) {
#pragma unroll
    for (int n = 0; n < 4; ++n) {
      const int grow0 = row0 + wm * 64 + m * 16 + (lane >> 4) * 4;
      const int gcol = col0 + wn * 64 + n * 16 + (lane & 15);
#pragma unroll
      for (int r = 0; r < 4; ++r)
        C[(size_t)(grow0 + r) * Nc + gcol] = acc[m][n][r];
    }
  }
}

// ======================= fused split (all fp16) =======================
struct SplitDesc {
  const float* src[7];
  f16_t* hi[7];
  f16_t* lo[7];
  int mode[7];
  int blk_start[8];
};

__global__ __launch_bounds__(256)
void split_all(SplitDesc d)
{
  const int b = blockIdx.x;
  int seg = 0;
#pragma unroll
  for (int s = 1; s < 7; ++s) seg += (b >= d.blk_start[s]) ? 1 : 0;
  const int i = (b - d.blk_start[seg]) * 256 + threadIdx.x;
  const float4 v = ((const float4*)d.src[seg])[i];
  const float vv[4] = {v.x, v.y, v.z, v.w};
  f16x4 h, l;
#pragma unroll
  for (int j = 0; j < 4; ++j) {
    const f16_t hh = (f16_t)vv[j];
    h[j] = hh;
    l[j] = (f16_t)(vv[j] - (float)hh);
  }
  ((f16x4*)d.hi[seg])[i] = h;
  if (d.mode[seg] == 2) ((f16x4*)d.lo[seg])[i] = l;
}

// ======================= softmax (fp32 in-place + fp16 P) =======================
__global__ __launch_bounds__(256)
void softmax_rows(float* __restrict__ S, f16_t* __restrict__ P, int n)
{
  const int row = blockIdx.x;
  float* srow = S + (size_t)row * n;
  f16_t* prow = P + (size_t)row * n;
  const int t = threadIdx.x;
  const int lane = t & 63;
  const int wave = t >> 6;
  __shared__ float red[8];

  float4 v[4];
  float mx = -3.4e38f;
#pragma unroll
  for (int i = 0; i < 4; ++i) {
    v[i] = *(const float4*)(srow + (size_t)(i * 256 + t) * 4);
    mx = fmaxf(mx, fmaxf(fmaxf(v[i].x, v[i].y), fmaxf(v[i].z, v[i].w)));
  }
#pragma unroll
  for (int off = 32; off > 0; off >>= 1) mx = fmaxf(mx, __shfl_xor(mx, off));
  if (lane == 0) red[wave] = mx;
  __syncthreads();
  mx = fmaxf(fmaxf(red[0], red[1]), fmaxf(red[2], red[3]));

  float e[16];
  float sum = 0.f;
#pragma unroll
  for (int i = 0; i < 4; ++i) {
    e[4 * i + 0] = __expf(v[i].x - mx);
    e[4 * i + 1] = __expf(v[i].y - mx);
    e[4 * i + 2] = __expf(v[i].z - mx);
    e[4 * i + 3] = __expf(v[i].w - mx);
    sum += e[4 * i + 0] + e[4 * i + 1] + e[4 * i + 2] + e[4 * i + 3];
  }
#pragma unroll
  for (int off = 32; off > 0; off >>= 1) sum += __shfl_xor(sum, off);
  if (lane == 0) red[4 + wave] = sum;
  __syncthreads();
  sum = red[4] + red[5] + red[6] + red[7];
  const float inv = 1.0f / sum;

#pragma unroll
  for (int i = 0; i < 4; ++i) {
    float4 w;
    w.x = e[4 * i + 0] * inv;
    w.y = e[4 * i + 1] * inv;
    w.z = e[4 * i + 2] * inv;
    w.w = e[4 * i + 3] * inv;
    *(float4*)(srow + (size_t)(i * 256 + t) * 4) = w;
    f16x4 p;
    p[0] = (f16_t)w.x;
    p[1] = (f16_t)w.y;
    p[2] = (f16_t)w.z;
    p[3] = (f16_t)w.w;
    *(f16x4*)(prow + (size_t)(i * 256 + t) * 4) = p;
  }
}

extern "C" void kernel_launch(void* const* d_in, const int* in_sizes, int n_in,
                              void* d_out, int out_size, void* d_ws, size_t ws_size,
                              hipStream_t stream) {
  const int N = N_SEQ, D = DMODEL;
  const float* q    = (const float*)d_in[0];
  const float* k    = (const float*)d_in[1];
  const float* v    = (const float*)d_in[2];
  const float* wq_w = (const float*)d_in[3];
  const float* wq_b = (const float*)d_in[4];
  const float* wk_w = (const float*)d_in[5];
  const float* wk_b = (const float*)d_in[6];
  const float* wv_w = (const float*)d_in[7];
  const float* wv_b = (const float*)d_in[8];
  const float* wo_w = (const float*)d_in[9];
  const float* wo_b = (const float*)d_in[10];

  float* x_out = (float*)d_out;                 // [N, D]
  float* attn  = x_out + (size_t)N * D;         // [N, N]

  char* wsp = (char*)d_ws;
  auto alloc = [&](size_t bytes) { char* p = wsp; wsp += bytes; return p; };
  const size_t ND = (size_t)N * D, DD = (size_t)D * D;
  f16_t*  qh16  = (f16_t*)alloc(ND * 2);
  f16_t*  ql16  = (f16_t*)alloc(ND * 2);
  f16_t*  kh16  = (f16_t*)alloc(ND * 2);
  f16_t*  kl16  = (f16_t*)alloc(ND * 2);
  f16_t*  vh16  = (f16_t*)alloc(ND * 2);
  f16_t*  wq16  = (f16_t*)alloc(DD * 2);
  f16_t*  wk16  = (f16_t*)alloc(DD * 2);
  f16_t*  wv16  = (f16_t*)alloc(DD * 2);
  f16_t*  wo16  = (f16_t*)alloc(DD * 2);
  f16_t*  QPh   = (f16_t*)alloc(ND * 2);        // fp16 qp
  f16_t*  pad1  = (f16_t*)alloc(ND * 2);
  f16_t*  KPh   = (f16_t*)alloc(ND * 2);        // fp16 kp
  f16_t*  pad2  = (f16_t*)alloc(ND * 2);
  f16_t*  VPt   = (f16_t*)alloc(ND * 2);        // [D][N] transposed fp16
  // aliases (producers run strictly after last readers of the underlying bufs)
  f16_t*  Pb    = QPh;    // 32 MB over QPh..pad2 (dead after scores)
  f16_t*  Xb    = vh16;   // 8 MB over vh16 (dead after qkv_proj)
  (void)pad1; (void)pad2;

  // fused split: q,k -> fp16 hi+lo; v + all weights -> single fp16
  SplitDesc sd;
  sd.src[0] = q;    sd.hi[0] = qh16;  sd.lo[0] = ql16;    sd.mode[0] = 2;
  sd.src[1] = k;    sd.hi[1] = kh16;  sd.lo[1] = kl16;    sd.mode[1] = 2;
  sd.src[2] = v;    sd.hi[2] = vh16;  sd.lo[2] = nullptr; sd.mode[2] = 3;
  sd.src[3] = wq_w; sd.hi[3] = wq16;  sd.lo[3] = nullptr; sd.mode[3] = 3;
  sd.src[4] = wk_w; sd.hi[4] = wk16;  sd.lo[4] = nullptr; sd.mode[4] = 3;
  sd.src[5] = wv_w; sd.hi[5] = wv16;  sd.lo[5] = nullptr; sd.mode[5] = 3;
  sd.src[6] = wo_w; sd.hi[6] = wo16;  sd.lo[6] = nullptr; sd.mode[6] = 3;
  const int nb_nd = (int)(ND / 4 / 256);   // 4096
  const int nb_dd = (int)(DD / 4 / 256);   // 1024
  sd.blk_start[0] = 0;
  sd.blk_start[1] = nb_nd;
  sd.blk_start[2] = 2 * nb_nd;
  sd.blk_start[3] = 3 * nb_nd;
  sd.blk_start[4] = 3 * nb_nd + nb_dd;
  sd.blk_start[5] = 3 * nb_nd + 2 * nb_dd;
  sd.blk_start[6] = 3 * nb_nd + 3 * nb_dd;
  sd.blk_start[7] = 3 * nb_nd + 4 * nb_dd;
  split_all<<<dim3(sd.blk_start[7]), dim3(256), 0, stream>>>(sd);

  const dim3 blk(256);
  const dim3 gsc(N / BN, N / BM);      // (32, 32) = 1024 blocks
  const dim3 gd(D / BN2, N / BM);      // (16, 32) = 512 blocks

  // fused Q/K/V projections: Q 2-pass, K 2-pass, V 1-pass (48 KiB LDS)
  qkv_proj<<<dim3(D / BN, N / BM, 3), blk, 0, stream>>>(
      qh16, ql16, wq16, wq_b,
      kh16, kl16, wk16, wk_b,
      vh16, wv16, wv_b,
      QPh, KPh, VPt);

  // scores = QPh @ KPh^T  (128x128 pipelined, K=1024, fp32 into d_out)
  gemm_f16s<<<gsc, blk, 0, stream>>>(QPh, KPh, attn, N, N, D);

  // softmax rows in-place + fp16 copy (Pb aliases QP/KP region: dead now)
  softmax_rows<<<dim3(N), blk, 0, stream>>>(attn, Pb, N);

  // X = P @ VP  (pipelined dbuf BK=64, full K=4096 -> fp16 Xb)
  gemm_f16p<0><<<gd, blk, 0, stream>>>(
      Pb, VPt, nullptr, Xb, nullptr, N, D, N);

  // out = X @ wo^T + b  (pipelined dbuf BK=64, K=1024 -> fp32 d_out + bias)
  gemm_f16p<1><<<gd, blk, 0, stream>>>(
      Xb, wo16, wo_b, nullptr, x_out, N, D, D);
}

// Round 21
// 200.327 us; speedup vs baseline: 1.0089x; 1.0089x over previous
//
#include <hip/hip_runtime.h>
#include <cstdint>

// Problem constants (fixed by the reference)
#define N_SEQ 4096
#define DMODEL 1024

#define BM 128
#define BN 128
#define BN2 64
#define UNITE 4096   // one 64x64 f16 unit (8 KiB)

typedef __bf16 bf16_t;
typedef _Float16 f16_t;
typedef f16_t f16x8 __attribute__((ext_vector_type(8)));
typedef f16_t f16x4 __attribute__((ext_vector_type(4)));
typedef float f32x4 __attribute__((ext_vector_type(4)));

typedef __attribute__((address_space(1))) void* as1ptr;
typedef __attribute__((address_space(3))) void* as3ptr;

__device__ __forceinline__ void gload16(const void* g, void* l) {
  __builtin_amdgcn_global_load_lds((as1ptr)(uintptr_t)g, (as3ptr)(uintptr_t)l,
                                   16, 0, 0);
}

#define SBAR() asm volatile("s_barrier" ::: "memory")
#define WAITLGKM(n)                                              \
  do {                                                           \
    asm volatile("s_waitcnt lgkmcnt(" #n ")" ::: "memory");      \
    __builtin_amdgcn_sched_barrier(0);                           \
  } while (0)
#define WAITVM(n) asm volatile("s_waitcnt vmcnt(" #n ")" ::: "memory")

// ================= fused QKV projection, pipelined (z = 0:Q, 1:K, 2:V) =====
// gemm_f16s schedule (128x128 tile, BK=64 dbuf, counted vmcnt) with logical-K
// segments for the 2-pass projections:
//   z=0 (Q): NT=32, kt<16 -> qh@wq, kt>=16 -> ql@wq   -> fp16 QPh
//   z=1 (K): NT=32, kt<16 -> kh@wk, kt>=16 -> kl@wk   -> fp16 KPh
//   z=2 (V): NT=16, vh@wv                              -> fp16 transposed VPt
// LDS 64 KiB -> 2 blocks/CU.  B re-staged per segment (L2-resident weights).
__global__ __launch_bounds__(256)
void qkv_proj(const f16_t* __restrict__ qh, const f16_t* __restrict__ ql,
              const f16_t* __restrict__ wq, const float* __restrict__ wq_b,
              const f16_t* __restrict__ kh, const f16_t* __restrict__ kl,
              const f16_t* __restrict__ wk, const float* __restrict__ wk_b,
              const f16_t* __restrict__ vh, const f16_t* __restrict__ wv,
              const float* __restrict__ wv_b,
              f16_t* __restrict__ QPh, f16_t* __restrict__ KPh,
              f16_t* __restrict__ VPt)
{
  __shared__ __align__(16) f16_t lds[2 * 4 * UNITE];   // 64 KiB

  const int z = blockIdx.z;
  const f16_t *A0, *A1 = nullptr, *B0;
  const float* bias;
  if (z == 0)      { A0 = qh; A1 = ql; B0 = wq; bias = wq_b; }
  else if (z == 1) { A0 = kh; A1 = kl; B0 = wk; bias = wk_b; }
  else             { A0 = vh; A1 = vh; B0 = wv; bias = wv_b; }
  const int NT = (z < 2) ? 32 : 16;

  const int M = N_SEQ, Nc = DMODEL, K = DMODEL;
  const int t = threadIdx.x;
  const int lane = t & 63;
  const int wave = t >> 6;
  const int wm = wave >> 1;     // 0..1 (64-row half)
  const int wn = wave & 1;      // 0..1 (64-col half)

  // XCD-aware swizzle within the 8x32 (x,y) plane (256 blocks, bijective)
  const int gx = gridDim.x;                       // 8
  const int nwg = gx * gridDim.y;                 // 256
  const int flat = blockIdx.y * gx + blockIdx.x;
  const int swz = (flat & 7) * (nwg >> 3) + (flat >> 3);
  const int row0 = (swz / gx) * BM;
  const int col0 = (swz % gx) * BN;

  const int srw = t >> 3;                                // 0..31
  const int scol = 8 * ((t & 7) ^ ((t >> 3) & 7));       // pre-swizzled src
  const int sdst = t * 8;

  const int fr = lane & 15;
  const int kq = (lane >> 4) * 8;
  const int sw = (fr & 7) << 3;                          // read-side swizzle

  auto stage = [&](int buf, int kt) {
    const f16_t* A = (kt >= 16) ? A1 : A0;
    const int k0 = (kt & 15) << 6;
#pragma unroll
    for (int h = 0; h < 2; ++h) {
      const int r = h * 32 + srw;
      gload16(A + (size_t)(row0 + r) * K + k0 + scol,
              &lds[(buf * 4 + 0) * UNITE + h * 2048 + sdst]);
      gload16(A + (size_t)(row0 + 64 + r) * K + k0 + scol,
              &lds[(buf * 4 + 1) * UNITE + h * 2048 + sdst]);
      gload16(B0 + (size_t)(col0 + r) * K + k0 + scol,
              &lds[(buf * 4 + 2) * UNITE + h * 2048 + sdst]);
      gload16(B0 + (size_t)(col0 + 64 + r) * K + k0 + scol,
              &lds[(buf * 4 + 3) * UNITE + h * 2048 + sdst]);
    }
  };

  f32x4 acc[4][4] = {};

  stage(0, 0);
  stage(1, 1);
  WAITVM(8);
  SBAR();

  for (int kt = 0; kt < NT; ++kt) {
    const int p = kt & 1;
    const f16_t* Ab = &lds[(p * 4 + wm) * UNITE];
    const f16_t* Bb = &lds[(p * 4 + 2 + wn) * UNITE];

    f16x8 ah[4][2], bh[4][2];
#pragma unroll
    for (int m = 0; m < 4; ++m)
#pragma unroll
      for (int ks = 0; ks < 2; ++ks)
        ah[m][ks] = *(const f16x8*)&Ab[(m * 16 + fr) * 64 +
                                       ((ks * 32 + kq) ^ sw)];
#pragma unroll
    for (int n = 0; n < 2; ++n)
#pragma unroll
      for (int ks = 0; ks < 2; ++ks)
        bh[n][ks] = *(const f16x8*)&Bb[(n * 16 + fr) * 64 +
                                       ((ks * 32 + kq) ^ sw)];
#pragma unroll
    for (int n = 2; n < 4; ++n)
#pragma unroll
      for (int ks = 0; ks < 2; ++ks)
        bh[n][ks] = *(const f16x8*)&Bb[(n * 16 + fr) * 64 +
                                       ((ks * 32 + kq) ^ sw)];

    WAITLGKM(4);
#pragma unroll
    for (int m = 0; m < 4; ++m)
#pragma unroll
      for (int n = 0; n < 2; ++n)
#pragma unroll
        for (int ks = 0; ks < 2; ++ks)
          acc[m][n] = __builtin_amdgcn_mfma_f32_16x16x32_f16(
              ah[m][ks], bh[n][ks], acc[m][n], 0, 0, 0);
    WAITLGKM(0);
#pragma unroll
    for (int m = 0; m < 4; ++m)
#pragma unroll
      for (int n = 2; n < 4; ++n)
#pragma unroll
        for (int ks = 0; ks < 2; ++ks)
          acc[m][n] = __builtin_amdgcn_mfma_f32_16x16x32_f16(
              ah[m][ks], bh[n][ks], acc[m][n], 0, 0, 0);

    SBAR();
    if (kt + 2 < NT) {
      stage(p, kt + 2);
      WAITVM(8);
    } else if (kt + 1 < NT) {
      WAITVM(0);
    }
    SBAR();
  }

#pragma unroll
  for (int m = 0; m < 4; ++m) {
#pragma unroll
    for (int n = 0; n < 4; ++n) {
      const int grow0 = row0 + wm * 64 + m * 16 + (lane >> 4) * 4;
      const int gcol = col0 + wn * 64 + n * 16 + (lane & 15);
      const float bv = bias[gcol];
      if (z == 2) {
        f16x4 p;
#pragma unroll
        for (int r = 0; r < 4; ++r) p[r] = (f16_t)(acc[m][n][r] + bv);
        *(f16x4*)&VPt[(size_t)gcol * M + grow0] = p;
      } else {
        f16_t* out = (z == 0) ? QPh : KPh;
#pragma unroll
        for (int r = 0; r < 4; ++r)
          out[(size_t)(grow0 + r) * Nc + gcol] = (f16_t)(acc[m][n][r] + bv);
      }
    }
  }
}

// ====== pipelined fp16 GEMM, 128x64 tile, BK=64 double-buffered ======
template <int OUT_F32>
__global__ __launch_bounds__(256)
void gemm_f16p(const f16_t* __restrict__ A, const f16_t* __restrict__ B,
               const float* __restrict__ bias,
               f16_t* __restrict__ Cf16, float* __restrict__ Cf32,
               int M, int Nc, int K)
{
  __shared__ __align__(16) f16_t lds[2 * 3 * UNITE];   // 48 KiB

  const int gx = gridDim.x;
  const int nwg = gx * gridDim.y;
  const int flat = blockIdx.y * gx + blockIdx.x;
  const int swz = (flat & 7) * (nwg >> 3) + (flat >> 3);
  const int bx = swz % gx;
  const int by = swz / gx;

  const int t = threadIdx.x;
  const int lane = t & 63;
  const int wave = t >> 6;
  const int wm = wave >> 1;
  const int wn = wave & 1;
  const int row0 = by * BM;
  const int col0 = bx * BN2;

  const int srw = t >> 3;
  const int scol = 8 * ((t & 7) ^ ((t >> 3) & 7));
  const int sdst = t * 8;

  const int fr = lane & 15;
  const int kq = (lane >> 4) * 8;
  const int sw = (fr & 7) << 3;

  auto stage = [&](int buf, int kt) {
    const int k0 = kt << 6;
#pragma unroll
    for (int h = 0; h < 2; ++h) {
      const int r = h * 32 + srw;
      gload16(A + (size_t)(row0 + r) * K + k0 + scol,
              &lds[(buf * 3 + 0) * UNITE + h * 2048 + sdst]);
      gload16(A + (size_t)(row0 + 64 + r) * K + k0 + scol,
              &lds[(buf * 3 + 1) * UNITE + h * 2048 + sdst]);
      gload16(B + (size_t)(col0 + r) * K + k0 + scol,
              &lds[(buf * 3 + 2) * UNITE + h * 2048 + sdst]);
    }
  };

  f32x4 acc[4][2] = {};
  const int NT = K >> 6;

  stage(0, 0);
  stage(1, 1);
  WAITVM(6);
  SBAR();

  for (int kt = 0; kt < NT; ++kt) {
    const int p = kt & 1;
    const f16_t* Ab = &lds[(p * 3 + wm) * UNITE];
    const f16_t* Bb = &lds[(p * 3 + 2) * UNITE];

    f16x8 ah[4][2], bh[2][2];
#pragma unroll
    for (int m = 0; m < 2; ++m)
#pragma unroll
      for (int ks = 0; ks < 2; ++ks)
        ah[m][ks] = *(const f16x8*)&Ab[(m * 16 + fr) * 64 +
                                       ((ks * 32 + kq) ^ sw)];
#pragma unroll
    for (int n = 0; n < 2; ++n)
#pragma unroll
      for (int ks = 0; ks < 2; ++ks)
        bh[n][ks] = *(const f16x8*)&Bb[(wn * 32 + n * 16 + fr) * 64 +
                                       ((ks * 32 + kq) ^ sw)];
#pragma unroll
    for (int m = 2; m < 4; ++m)
#pragma unroll
      for (int ks = 0; ks < 2; ++ks)
        ah[m][ks] = *(const f16x8*)&Ab[(m * 16 + fr) * 64 +
                                       ((ks * 32 + kq) ^ sw)];

    WAITLGKM(4);
#pragma unroll
    for (int m = 0; m < 2; ++m)
#pragma unroll
      for (int n = 0; n < 2; ++n)
#pragma unroll
        for (int ks = 0; ks < 2; ++ks)
          acc[m][n] = __builtin_amdgcn_mfma_f32_16x16x32_f16(
              ah[m][ks], bh[n][ks], acc[m][n], 0, 0, 0);
    WAITLGKM(0);
#pragma unroll
    for (int m = 2; m < 4; ++m)
#pragma unroll
      for (int n = 0; n < 2; ++n)
#pragma unroll
        for (int ks = 0; ks < 2; ++ks)
          acc[m][n] = __builtin_amdgcn_mfma_f32_16x16x32_f16(
              ah[m][ks], bh[n][ks], acc[m][n], 0, 0, 0);

    SBAR();
    if (kt + 2 < NT) {
      stage(p, kt + 2);
      WAITVM(6);
    } else if (kt + 1 < NT) {
      WAITVM(0);
    }
    SBAR();
  }

#pragma unroll
  for (int m = 0; m < 4; ++m) {
#pragma unroll
    for (int n = 0; n < 2; ++n) {
      const int grow0 = row0 + wm * 64 + m * 16 + (lane >> 4) * 4;
      const int gcol = col0 + wn * 32 + n * 16 + (lane & 15);
#pragma unroll
      for (int r = 0; r < 4; ++r) {
        const size_t idx = (size_t)(grow0 + r) * Nc + gcol;
        if (OUT_F32) Cf32[idx] = acc[m][n][r] + bias[gcol];
        else         Cf16[idx] = (f16_t)acc[m][n][r];
      }
    }
  }
}

// ====== pipelined fp16 scores GEMM, 128x128 tile, BK=64 dbuf -> fp32 ======
__global__ __launch_bounds__(256)
void gemm_f16s(const f16_t* __restrict__ A, const f16_t* __restrict__ B,
               float* __restrict__ C, int M, int Nc, int K)
{
  __shared__ __align__(16) f16_t lds[2 * 4 * UNITE];   // 64 KiB

  const int gx = gridDim.x;
  const int nwg = gx * gridDim.y;
  const int flat = blockIdx.y * gx + blockIdx.x;
  const int swz = (flat & 7) * (nwg >> 3) + (flat >> 3);
  const int bx = swz % gx;
  const int by = swz / gx;

  const int t = threadIdx.x;
  const int lane = t & 63;
  const int wave = t >> 6;
  const int wm = wave >> 1;
  const int wn = wave & 1;
  const int row0 = by * BM;
  const int col0 = bx * BN;

  const int srw = t >> 3;
  const int scol = 8 * ((t & 7) ^ ((t >> 3) & 7));
  const int sdst = t * 8;

  const int fr = lane & 15;
  const int kq = (lane >> 4) * 8;
  const int sw = (fr & 7) << 3;

  auto stage = [&](int buf, int kt) {
    const int k0 = kt << 6;
#pragma unroll
    for (int h = 0; h < 2; ++h) {
      const int r = h * 32 + srw;
      gload16(A + (size_t)(row0 + r) * K + k0 + scol,
              &lds[(buf * 4 + 0) * UNITE + h * 2048 + sdst]);
      gload16(A + (size_t)(row0 + 64 + r) * K + k0 + scol,
              &lds[(buf * 4 + 1) * UNITE + h * 2048 + sdst]);
      gload16(B + (size_t)(col0 + r) * K + k0 + scol,
              &lds[(buf * 4 + 2) * UNITE + h * 2048 + sdst]);
      gload16(B + (size_t)(col0 + 64 + r) * K + k0 + scol,
              &lds[(buf * 4 + 3) * UNITE + h * 2048 + sdst]);
    }
  };

  f32x4 acc[4][4] = {};
  const int NT = K >> 6;   // 16

  stage(0, 0);
  stage(1, 1);
  WAITVM(8);
  SBAR();

  for (int kt = 0; kt < NT; ++kt) {
    const int p = kt & 1;
    const f16_t* Ab = &lds[(p * 4 + wm) * UNITE];
    const f16_t* Bb = &lds[(p * 4 + 2 + wn) * UNITE];

    f16x8 ah[4][2], bh[4][2];
#pragma unroll
    for (int m = 0; m < 4; ++m)
#pragma unroll
      for (int ks = 0; ks < 2; ++ks)
        ah[m][ks] = *(const f16x8*)&Ab[(m * 16 + fr) * 64 +
                                       ((ks * 32 + kq) ^ sw)];
#pragma unroll
    for (int n = 0; n < 2; ++n)
#pragma unroll
      for (int ks = 0; ks < 2; ++ks)
        bh[n][ks] = *(const f16x8*)&Bb[(n * 16 + fr) * 64 +
                                       ((ks * 32 + kq) ^ sw)];
#pragma unroll
    for (int n = 2; n < 4; ++n)
#pragma unroll
      for (int ks = 0; ks < 2; ++ks)
        bh[n][ks] = *(const f16x8*)&Bb[(n * 16 + fr) * 64 +
                                       ((ks * 32 + kq) ^ sw)];

    WAITLGKM(4);
#pragma unroll
    for (int m = 0; m < 4; ++m)
#pragma unroll
      for (int n = 0; n < 2; ++n)
#pragma unroll
        for (int ks = 0; ks < 2; ++ks)
          acc[m][n] = __builtin_amdgcn_mfma_f32_16x16x32_f16(
              ah[m][ks], bh[n][ks], acc[m][n], 0, 0, 0);
    WAITLGKM(0);
#pragma unroll
    for (int m = 0; m < 4; ++m)
#pragma unroll
      for (int n = 2; n < 4; ++n)
#pragma unroll
        for (int ks = 0; ks < 2; ++ks)
          acc[m][n] = __builtin_amdgcn_mfma_f32_16x16x32_f16(
              ah[m][ks], bh[n][ks], acc[m][n], 0, 0, 0);

    SBAR();
    if (kt + 2 < NT) {
      stage(p, kt + 2);
      WAITVM(8);
    } else if (kt + 1 < NT) {
      WAITVM(0);
    }
    SBAR();
  }

#pragma unroll
  for (int m = 0; m < 4; ++m) {
#pragma unroll
    for (int n = 0; n < 4; ++n) {
      const int grow0 = row0 + wm * 64 + m * 16 + (lane >> 4) * 4;
      const int gcol = col0 + wn * 64 + n * 16 + (lane & 15);
#pragma unroll
      for (int r = 0; r < 4; ++r)
        C[(size_t)(grow0 + r) * Nc + gcol] = acc[m][n][r];
    }
  }
}

// ======================= fused split (all fp16) =======================
struct SplitDesc {
  const float* src[7];
  f16_t* hi[7];
  f16_t* lo[7];
  int mode[7];
  int blk_start[8];
};

__global__ __launch_bounds__(256)
void split_all(SplitDesc d)
{
  const int b = blockIdx.x;
  int seg = 0;
#pragma unroll
  for (int s = 1; s < 7; ++s) seg += (b >= d.blk_start[s]) ? 1 : 0;
  const int i = (b - d.blk_start[seg]) * 256 + threadIdx.x;
  const float4 v = ((const float4*)d.src[seg])[i];
  const float vv[4] = {v.x, v.y, v.z, v.w};
  f16x4 h, l;
#pragma unroll
  for (int j = 0; j < 4; ++j) {
    const f16_t hh = (f16_t)vv[j];
    h[j] = hh;
    l[j] = (f16_t)(vv[j] - (float)hh);
  }
  ((f16x4*)d.hi[seg])[i] = h;
  if (d.mode[seg] == 2) ((f16x4*)d.lo[seg])[i] = l;
}

// ======================= softmax (fp32 in-place + fp16 P) =======================
__global__ __launch_bounds__(256)
void softmax_rows(float* __restrict__ S, f16_t* __restrict__ P, int n)
{
  const int row = blockIdx.x;
  float* srow = S + (size_t)row * n;
  f16_t* prow = P + (size_t)row * n;
  const int t = threadIdx.x;
  const int lane = t & 63;
  const int wave = t >> 6;
  __shared__ float red[8];

  float4 v[4];
  float mx = -3.4e38f;
#pragma unroll
  for (int i = 0; i < 4; ++i) {
    v[i] = *(const float4*)(srow + (size_t)(i * 256 + t) * 4);
    mx = fmaxf(mx, fmaxf(fmaxf(v[i].x, v[i].y), fmaxf(v[i].z, v[i].w)));
  }
#pragma unroll
  for (int off = 32; off > 0; off >>= 1) mx = fmaxf(mx, __shfl_xor(mx, off));
  if (lane == 0) red[wave] = mx;
  __syncthreads();
  mx = fmaxf(fmaxf(red[0], red[1]), fmaxf(red[2], red[3]));

  float e[16];
  float sum = 0.f;
#pragma unroll
  for (int i = 0; i < 4; ++i) {
    e[4 * i + 0] = __expf(v[i].x - mx);
    e[4 * i + 1] = __expf(v[i].y - mx);
    e[4 * i + 2] = __expf(v[i].z - mx);
    e[4 * i + 3] = __expf(v[i].w - mx);
    sum += e[4 * i + 0] + e[4 * i + 1] + e[4 * i + 2] + e[4 * i + 3];
  }
#pragma unroll
  for (int off = 32; off > 0; off >>= 1) sum += __shfl_xor(sum, off);
  if (lane == 0) red[4 + wave] = sum;
  __syncthreads();
  sum = red[4] + red[5] + red[6] + red[7];
  const float inv = 1.0f / sum;

#pragma unroll
  for (int i = 0; i < 4; ++i) {
    float4 w;
    w.x = e[4 * i + 0] * inv;
    w.y = e[4 * i + 1] * inv;
    w.z = e[4 * i + 2] * inv;
    w.w = e[4 * i + 3] * inv;
    *(float4*)(srow + (size_t)(i * 256 + t) * 4) = w;
    f16x4 p;
    p[0] = (f16_t)w.x;
    p[1] = (f16_t)w.y;
    p[2] = (f16_t)w.z;
    p[3] = (f16_t)w.w;
    *(f16x4*)(prow + (size_t)(i * 256 + t) * 4) = p;
  }
}

extern "C" void kernel_launch(void* const* d_in, const int* in_sizes, int n_in,
                              void* d_out, int out_size, void* d_ws, size_t ws_size,
                              hipStream_t stream) {
  const int N = N_SEQ, D = DMODEL;
  const float* q    = (const float*)d_in[0];
  const float* k    = (const float*)d_in[1];
  const float* v    = (const float*)d_in[2];
  const float* wq_w = (const float*)d_in[3];
  const float* wq_b = (const float*)d_in[4];
  const float* wk_w = (const float*)d_in[5];
  const float* wk_b = (const float*)d_in[6];
  const float* wv_w = (const float*)d_in[7];
  const float* wv_b = (const float*)d_in[8];
  const float* wo_w = (const float*)d_in[9];
  const float* wo_b = (const float*)d_in[10];

  float* x_out = (float*)d_out;                 // [N, D]
  float* attn  = x_out + (size_t)N * D;         // [N, N]

  char* wsp = (char*)d_ws;
  auto alloc = [&](size_t bytes) { char* p = wsp; wsp += bytes; return p; };
  const size_t ND = (size_t)N * D, DD = (size_t)D * D;
  f16_t*  qh16  = (f16_t*)alloc(ND * 2);
  f16_t*  ql16  = (f16_t*)alloc(ND * 2);
  f16_t*  kh16  = (f16_t*)alloc(ND * 2);
  f16_t*  kl16  = (f16_t*)alloc(ND * 2);
  f16_t*  vh16  = (f16_t*)alloc(ND * 2);
  f16_t*  wq16  = (f16_t*)alloc(DD * 2);
  f16_t*  wk16  = (f16_t*)alloc(DD * 2);
  f16_t*  wv16  = (f16_t*)alloc(DD * 2);
  f16_t*  wo16  = (f16_t*)alloc(DD * 2);
  f16_t*  QPh   = (f16_t*)alloc(ND * 2);        // fp16 qp
  f16_t*  pad1  = (f16_t*)alloc(ND * 2);
  f16_t*  KPh   = (f16_t*)alloc(ND * 2);        // fp16 kp
  f16_t*  pad2  = (f16_t*)alloc(ND * 2);
  f16_t*  VPt   = (f16_t*)alloc(ND * 2);        // [D][N] transposed fp16
  // aliases (producers run strictly after last readers of the underlying bufs)
  f16_t*  Pb    = QPh;    // 32 MB over QPh..pad2 (dead after scores)
  f16_t*  Xb    = vh16;   // 8 MB over vh16 (dead after qkv_proj)
  (void)pad1; (void)pad2;

  // fused split: q,k -> fp16 hi+lo; v + all weights -> single fp16
  SplitDesc sd;
  sd.src[0] = q;    sd.hi[0] = qh16;  sd.lo[0] = ql16;    sd.mode[0] = 2;
  sd.src[1] = k;    sd.hi[1] = kh16;  sd.lo[1] = kl16;    sd.mode[1] = 2;
  sd.src[2] = v;    sd.hi[2] = vh16;  sd.lo[2] = nullptr; sd.mode[2] = 3;
  sd.src[3] = wq_w; sd.hi[3] = wq16;  sd.lo[3] = nullptr; sd.mode[3] = 3;
  sd.src[4] = wk_w; sd.hi[4] = wk16;  sd.lo[4] = nullptr; sd.mode[4] = 3;
  sd.src[5] = wv_w; sd.hi[5] = wv16;  sd.lo[5] = nullptr; sd.mode[5] = 3;
  sd.src[6] = wo_w; sd.hi[6] = wo16;  sd.lo[6] = nullptr; sd.mode[6] = 3;
  const int nb_nd = (int)(ND / 4 / 256);   // 4096
  const int nb_dd = (int)(DD / 4 / 256);   // 1024
  sd.blk_start[0] = 0;
  sd.blk_start[1] = nb_nd;
  sd.blk_start[2] = 2 * nb_nd;
  sd.blk_start[3] = 3 * nb_nd;
  sd.blk_start[4] = 3 * nb_nd + nb_dd;
  sd.blk_start[5] = 3 * nb_nd + 2 * nb_dd;
  sd.blk_start[6] = 3 * nb_nd + 3 * nb_dd;
  sd.blk_start[7] = 3 * nb_nd + 4 * nb_dd;
  split_all<<<dim3(sd.blk_start[7]), dim3(256), 0, stream>>>(sd);

  const dim3 blk(256);
  const dim3 gsc(N / BN, N / BM);      // (32, 32) = 1024 blocks
  const dim3 gd(D / BN2, N / BM);      // (16, 32) = 512 blocks

  // fused Q/K/V projections: pipelined, logical-K segments (64 KiB LDS)
  qkv_proj<<<dim3(D / BN, N / BM, 3), blk, 0, stream>>>(
      qh16, ql16, wq16, wq_b,
      kh16, kl16, wk16, wk_b,
      vh16, wv16, wv_b,
      QPh, KPh, VPt);

  // scores = QPh @ KPh^T  (128x128 pipelined, K=1024, fp32 into d_out)
  gemm_f16s<<<gsc, blk, 0, stream>>>(QPh, KPh, attn, N, N, D);

  // softmax rows in-place + fp16 copy (Pb aliases QP/KP region: dead now)
  softmax_rows<<<dim3(N), blk, 0, stream>>>(attn, Pb, N);

  // X = P @ VP  (pipelined dbuf BK=64, full K=4096 -> fp16 Xb)
  gemm_f16p<0><<<gd, blk, 0, stream>>>(
      Pb, VPt, nullptr, Xb, nullptr, N, D, N);

  // out = X @ wo^T + b  (pipelined dbuf BK=64, K=1024 -> fp32 d_out + bias)
  gemm_f16p<1><<<gd, blk, 0, stream>>>(
      Xb, wo16, wo_b, nullptr, x_out, N, D, D);
}

// Round 22
// 196.179 us; speedup vs baseline: 1.0303x; 1.0211x over previous
//
#include <hip/hip_runtime.h>
#include <cstdint>

// Problem constants (fixed by the reference)
#define N_SEQ 4096
#define DMODEL 1024

#define BM 128
#define BN 128
#define BN2 64
#define UNITE 4096   // one 64x64 f16 unit (8 KiB)

typedef __bf16 bf16_t;
typedef _Float16 f16_t;
typedef f16_t f16x8 __attribute__((ext_vector_type(8)));
typedef f16_t f16x4 __attribute__((ext_vector_type(4)));
typedef float f32x4 __attribute__((ext_vector_type(4)));

typedef __attribute__((address_space(1))) void* as1ptr;
typedef __attribute__((address_space(3))) void* as3ptr;

__device__ __forceinline__ void gload16(const void* g, void* l) {
  __builtin_amdgcn_global_load_lds((as1ptr)(uintptr_t)g, (as3ptr)(uintptr_t)l,
                                   16, 0, 0);
}

#define SBAR() asm volatile("s_barrier" ::: "memory")
#define WAITLGKM(n)                                              \
  do {                                                           \
    asm volatile("s_waitcnt lgkmcnt(" #n ")" ::: "memory");      \
    __builtin_amdgcn_sched_barrier(0);                           \
  } while (0)
#define WAITVM(n) asm volatile("s_waitcnt vmcnt(" #n ")" ::: "memory")

// ================= fused QKV projection (z = 0:Q, 1:K, 2:V) =================
// All-fp16, BK=64 swizzled units.  LDS 48 KiB -> 3 blocks/CU.
// z=0 (Q, 2-pass): qp = (qh+ql)@wq^T + b -> fp16 QPh
// z=1 (K, 2-pass): kp = (kh+kl)@wk^T + b -> fp16 KPh
// z=2 (V, 1-pass): vp = vh@wv^T + b      -> fp16 transposed VPt
__global__ __launch_bounds__(256)
void qkv_proj(const f16_t* __restrict__ qh, const f16_t* __restrict__ ql,
              const f16_t* __restrict__ wq, const float* __restrict__ wq_b,
              const f16_t* __restrict__ kh, const f16_t* __restrict__ kl,
              const f16_t* __restrict__ wk, const float* __restrict__ wk_b,
              const f16_t* __restrict__ vh, const f16_t* __restrict__ wv,
              const float* __restrict__ wv_b,
              f16_t* __restrict__ QPh, f16_t* __restrict__ KPh,
              f16_t* __restrict__ VPt)
{
  __shared__ __align__(16) f16_t lds[6 * UNITE];   // 48 KiB

  const int z = blockIdx.z;
  const f16_t *A0, *A1 = nullptr, *B0;
  const float* bias;
  if (z == 0)      { A0 = qh; A1 = ql; B0 = wq; bias = wq_b; }
  else if (z == 1) { A0 = kh; A1 = kl; B0 = wk; bias = wk_b; }
  else             { A0 = vh;          B0 = wv; bias = wv_b; }
  const bool twop = (z < 2);

  const int M = N_SEQ, Nc = DMODEL, K = DMODEL;
  const int t = threadIdx.x;
  const int lane = t & 63;
  const int wave = t >> 6;
  const int wm = wave >> 1;
  const int wn = wave & 1;

  const int gx = gridDim.x;                       // 8
  const int nwg = gx * gridDim.y;                 // 256
  const int flat = blockIdx.y * gx + blockIdx.x;
  const int swz = (flat & 7) * (nwg >> 3) + (flat >> 3);
  const int row0 = (swz / gx) * BM;
  const int col0 = (swz % gx) * BN;

  const int srw = t >> 3;                                // 0..31
  const int scol = 8 * ((t & 7) ^ ((t >> 3) & 7));       // pre-swizzled src
  const int sdst = t * 8;

  const int fr = lane & 15;
  const int kq = (lane >> 4) * 8;
  const int sw = (fr & 7) << 3;                          // read-side swizzle

  f32x4 acc[4][4] = {};

  for (int k0 = 0; k0 < K; k0 += 64) {
#pragma unroll
    for (int h = 0; h < 2; ++h) {
      const int r = h * 32 + srw;
      gload16(A0 + (size_t)(row0 + r) * K + k0 + scol,
              &lds[0 * UNITE + h * 2048 + sdst]);
      gload16(A0 + (size_t)(row0 + 64 + r) * K + k0 + scol,
              &lds[1 * UNITE + h * 2048 + sdst]);
      gload16(B0 + (size_t)(col0 + r) * K + k0 + scol,
              &lds[4 * UNITE + h * 2048 + sdst]);
      gload16(B0 + (size_t)(col0 + 64 + r) * K + k0 + scol,
              &lds[5 * UNITE + h * 2048 + sdst]);
      if (twop) {
        gload16(A1 + (size_t)(row0 + r) * K + k0 + scol,
                &lds[2 * UNITE + h * 2048 + sdst]);
        gload16(A1 + (size_t)(row0 + 64 + r) * K + k0 + scol,
                &lds[3 * UNITE + h * 2048 + sdst]);
      }
    }
    __syncthreads();

    f16x8 ah[4][2], al[4][2], bh[4][2];
#pragma unroll
    for (int m = 0; m < 4; ++m) {
      const int r = (m * 16 + fr) * 64;
#pragma unroll
      for (int ks = 0; ks < 2; ++ks) {
        const int c = (ks * 32 + kq) ^ sw;
        ah[m][ks] = *(const f16x8*)&lds[wm * UNITE + r + c];
        if (twop) al[m][ks] = *(const f16x8*)&lds[(2 + wm) * UNITE + r + c];
      }
    }
#pragma unroll
    for (int n = 0; n < 4; ++n) {
      const int r = (n * 16 + fr) * 64;
#pragma unroll
      for (int ks = 0; ks < 2; ++ks)
        bh[n][ks] = *(const f16x8*)&lds[(4 + wn) * UNITE + r +
                                        (((ks * 32 + kq)) ^ sw)];
    }

#pragma unroll
    for (int m = 0; m < 4; ++m)
#pragma unroll
      for (int n = 0; n < 4; ++n)
#pragma unroll
        for (int ks = 0; ks < 2; ++ks) {
          acc[m][n] = __builtin_amdgcn_mfma_f32_16x16x32_f16(
              ah[m][ks], bh[n][ks], acc[m][n], 0, 0, 0);
          if (twop)
            acc[m][n] = __builtin_amdgcn_mfma_f32_16x16x32_f16(
                al[m][ks], bh[n][ks], acc[m][n], 0, 0, 0);
        }
    __syncthreads();
  }

#pragma unroll
  for (int m = 0; m < 4; ++m) {
#pragma unroll
    for (int n = 0; n < 4; ++n) {
      const int grow0 = row0 + wm * 64 + m * 16 + (lane >> 4) * 4;
      const int gcol = col0 + wn * 64 + n * 16 + (lane & 15);
      const float bv = bias[gcol];
      if (z == 2) {
        f16x4 p;
#pragma unroll
        for (int r = 0; r < 4; ++r) p[r] = (f16_t)(acc[m][n][r] + bv);
        *(f16x4*)&VPt[(size_t)gcol * M + grow0] = p;
      } else {
        f16_t* out = (z == 0) ? QPh : KPh;
#pragma unroll
        for (int r = 0; r < 4; ++r)
          out[(size_t)(grow0 + r) * Nc + gcol] = (f16_t)(acc[m][n][r] + bv);
      }
    }
  }
}

// ====== pipelined fp16 GEMM, 128x64 tile, BK=64 double-buffered ======
template <int OUT_F32>
__global__ __launch_bounds__(256)
void gemm_f16p(const f16_t* __restrict__ A, const f16_t* __restrict__ B,
               const float* __restrict__ bias,
               f16_t* __restrict__ Cf16, float* __restrict__ Cf32,
               int M, int Nc, int K)
{
  __shared__ __align__(16) f16_t lds[2 * 3 * UNITE];   // 48 KiB

  const int gx = gridDim.x;
  const int nwg = gx * gridDim.y;
  const int flat = blockIdx.y * gx + blockIdx.x;
  const int swz = (flat & 7) * (nwg >> 3) + (flat >> 3);
  const int bx = swz % gx;
  const int by = swz / gx;

  const int t = threadIdx.x;
  const int lane = t & 63;
  const int wave = t >> 6;
  const int wm = wave >> 1;
  const int wn = wave & 1;
  const int row0 = by * BM;
  const int col0 = bx * BN2;

  const int srw = t >> 3;
  const int scol = 8 * ((t & 7) ^ ((t >> 3) & 7));
  const int sdst = t * 8;

  const int fr = lane & 15;
  const int kq = (lane >> 4) * 8;
  const int sw = (fr & 7) << 3;

  auto stage = [&](int buf, int kt) {
    const int k0 = kt << 6;
#pragma unroll
    for (int h = 0; h < 2; ++h) {
      const int r = h * 32 + srw;
      gload16(A + (size_t)(row0 + r) * K + k0 + scol,
              &lds[(buf * 3 + 0) * UNITE + h * 2048 + sdst]);
      gload16(A + (size_t)(row0 + 64 + r) * K + k0 + scol,
              &lds[(buf * 3 + 1) * UNITE + h * 2048 + sdst]);
      gload16(B + (size_t)(col0 + r) * K + k0 + scol,
              &lds[(buf * 3 + 2) * UNITE + h * 2048 + sdst]);
    }
  };

  f32x4 acc[4][2] = {};
  const int NT = K >> 6;

  stage(0, 0);
  stage(1, 1);
  WAITVM(6);
  SBAR();

  for (int kt = 0; kt < NT; ++kt) {
    const int p = kt & 1;
    const f16_t* Ab = &lds[(p * 3 + wm) * UNITE];
    const f16_t* Bb = &lds[(p * 3 + 2) * UNITE];

    f16x8 ah[4][2], bh[2][2];
#pragma unroll
    for (int m = 0; m < 2; ++m)
#pragma unroll
      for (int ks = 0; ks < 2; ++ks)
        ah[m][ks] = *(const f16x8*)&Ab[(m * 16 + fr) * 64 +
                                       ((ks * 32 + kq) ^ sw)];
#pragma unroll
    for (int n = 0; n < 2; ++n)
#pragma unroll
      for (int ks = 0; ks < 2; ++ks)
        bh[n][ks] = *(const f16x8*)&Bb[(wn * 32 + n * 16 + fr) * 64 +
                                       ((ks * 32 + kq) ^ sw)];
#pragma unroll
    for (int m = 2; m < 4; ++m)
#pragma unroll
      for (int ks = 0; ks < 2; ++ks)
        ah[m][ks] = *(const f16x8*)&Ab[(m * 16 + fr) * 64 +
                                       ((ks * 32 + kq) ^ sw)];

    WAITLGKM(4);
#pragma unroll
    for (int m = 0; m < 2; ++m)
#pragma unroll
      for (int n = 0; n < 2; ++n)
#pragma unroll
        for (int ks = 0; ks < 2; ++ks)
          acc[m][n] = __builtin_amdgcn_mfma_f32_16x16x32_f16(
              ah[m][ks], bh[n][ks], acc[m][n], 0, 0, 0);
    WAITLGKM(0);
#pragma unroll
    for (int m = 2; m < 4; ++m)
#pragma unroll
      for (int n = 0; n < 2; ++n)
#pragma unroll
        for (int ks = 0; ks < 2; ++ks)
          acc[m][n] = __builtin_amdgcn_mfma_f32_16x16x32_f16(
              ah[m][ks], bh[n][ks], acc[m][n], 0, 0, 0);

    SBAR();
    if (kt + 2 < NT) {
      stage(p, kt + 2);
      WAITVM(6);
    } else if (kt + 1 < NT) {
      WAITVM(0);
    }
    SBAR();
  }

#pragma unroll
  for (int m = 0; m < 4; ++m) {
#pragma unroll
    for (int n = 0; n < 2; ++n) {
      const int grow0 = row0 + wm * 64 + m * 16 + (lane >> 4) * 4;
      const int gcol = col0 + wn * 32 + n * 16 + (lane & 15);
#pragma unroll
      for (int r = 0; r < 4; ++r) {
        const size_t idx = (size_t)(grow0 + r) * Nc + gcol;
        if (OUT_F32) Cf32[idx] = acc[m][n][r] + bias[gcol];
        else         Cf16[idx] = (f16_t)acc[m][n][r];
      }
    }
  }
}

// ====== pipelined fp16 scores GEMM, 128x128 tile, BK=64 dbuf -> fp32 ======
__global__ __launch_bounds__(256)
void gemm_f16s(const f16_t* __restrict__ A, const f16_t* __restrict__ B,
               float* __restrict__ C, int M, int Nc, int K)
{
  __shared__ __align__(16) f16_t lds[2 * 4 * UNITE];   // 64 KiB

  const int gx = gridDim.x;
  const int nwg = gx * gridDim.y;
  const int flat = blockIdx.y * gx + blockIdx.x;
  const int swz = (flat & 7) * (nwg >> 3) + (flat >> 3);
  const int bx = swz % gx;
  const int by = swz / gx;

  const int t = threadIdx.x;
  const int lane = t & 63;
  const int wave = t >> 6;
  const int wm = wave >> 1;
  const int wn = wave & 1;
  const int row0 = by * BM;
  const int col0 = bx * BN;

  const int srw = t >> 3;
  const int scol = 8 * ((t & 7) ^ ((t >> 3) & 7));
  const int sdst = t * 8;

  const int fr = lane & 15;
  const int kq = (lane >> 4) * 8;
  const int sw = (fr & 7) << 3;

  auto stage = [&](int buf, int kt) {
    const int k0 = kt << 6;
#pragma unroll
    for (int h = 0; h < 2; ++h) {
      const int r = h * 32 + srw;
      gload16(A + (size_t)(row0 + r) * K + k0 + scol,
              &lds[(buf * 4 + 0) * UNITE + h * 2048 + sdst]);
      gload16(A + (size_t)(row0 + 64 + r) * K + k0 + scol,
              &lds[(buf * 4 + 1) * UNITE + h * 2048 + sdst]);
      gload16(B + (size_t)(col0 + r) * K + k0 + scol,
              &lds[(buf * 4 + 2) * UNITE + h * 2048 + sdst]);
      gload16(B + (size_t)(col0 + 64 + r) * K + k0 + scol,
              &lds[(buf * 4 + 3) * UNITE + h * 2048 + sdst]);
    }
  };

  f32x4 acc[4][4] = {};
  const int NT = K >> 6;   // 16

  stage(0, 0);
  stage(1, 1);
  WAITVM(8);
  SBAR();

  for (int kt = 0; kt < NT; ++kt) {
    const int p = kt & 1;
    const f16_t* Ab = &lds[(p * 4 + wm) * UNITE];
    const f16_t* Bb = &lds[(p * 4 + 2 + wn) * UNITE];

    f16x8 ah[4][2], bh[4][2];
#pragma unroll
    for (int m = 0; m < 4; ++m)
#pragma unroll
      for (int ks = 0; ks < 2; ++ks)
        ah[m][ks] = *(const f16x8*)&Ab[(m * 16 + fr) * 64 +
                                       ((ks * 32 + kq) ^ sw)];
#pragma unroll
    for (int n = 0; n < 2; ++n)
#pragma unroll
      for (int ks = 0; ks < 2; ++ks)
        bh[n][ks] = *(const f16x8*)&Bb[(n * 16 + fr) * 64 +
                                       ((ks * 32 + kq) ^ sw)];
#pragma unroll
    for (int n = 2; n < 4; ++n)
#pragma unroll
      for (int ks = 0; ks < 2; ++ks)
        bh[n][ks] = *(const f16x8*)&Bb[(n * 16 + fr) * 64 +
                                       ((ks * 32 + kq) ^ sw)];

    WAITLGKM(4);
#pragma unroll
    for (int m = 0; m < 4; ++m)
#pragma unroll
      for (int n = 0; n < 2; ++n)
#pragma unroll
        for (int ks = 0; ks < 2; ++ks)
          acc[m][n] = __builtin_amdgcn_mfma_f32_16x16x32_f16(
              ah[m][ks], bh[n][ks], acc[m][n], 0, 0, 0);
    WAITLGKM(0);
#pragma unroll
    for (int m = 0; m < 4; ++m)
#pragma unroll
      for (int n = 2; n < 4; ++n)
#pragma unroll
        for (int ks = 0; ks < 2; ++ks)
          acc[m][n] = __builtin_amdgcn_mfma_f32_16x16x32_f16(
              ah[m][ks], bh[n][ks], acc[m][n], 0, 0, 0);

    SBAR();
    if (kt + 2 < NT) {
      stage(p, kt + 2);
      WAITVM(8);
    } else if (kt + 1 < NT) {
      WAITVM(0);
    }
    SBAR();
  }

#pragma unroll
  for (int m = 0; m < 4; ++m) {
#pragma unroll
    for (int n = 0; n < 4; ++n) {
      const int grow0 = row0 + wm * 64 + m * 16 + (lane >> 4) * 4;
      const int gcol = col0 + wn * 64 + n * 16 + (lane & 15);
#pragma unroll
      for (int r = 0; r < 4; ++r)
        C[(size_t)(grow0 + r) * Nc + gcol] = acc[m][n][r];
    }
  }
}

// ======================= fused split (all fp16) =======================
struct SplitDesc {
  const float* src[7];
  f16_t* hi[7];
  f16_t* lo[7];
  int mode[7];
  int blk_start[8];
};

__global__ __launch_bounds__(256)
void split_all(SplitDesc d)
{
  const int b = blockIdx.x;
  int seg = 0;
#pragma unroll
  for (int s = 1; s < 7; ++s) seg += (b >= d.blk_start[s]) ? 1 : 0;
  const int i = (b - d.blk_start[seg]) * 256 + threadIdx.x;
  const float4 v = ((const float4*)d.src[seg])[i];
  const float vv[4] = {v.x, v.y, v.z, v.w};
  f16x4 h, l;
#pragma unroll
  for (int j = 0; j < 4; ++j) {
    const f16_t hh = (f16_t)vv[j];
    h[j] = hh;
    l[j] = (f16_t)(vv[j] - (float)hh);
  }
  ((f16x4*)d.hi[seg])[i] = h;
  if (d.mode[seg] == 2) ((f16x4*)d.lo[seg])[i] = l;
}

// ======================= softmax (fp32 in-place + fp16 P) =======================
__global__ __launch_bounds__(256)
void softmax_rows(float* __restrict__ S, f16_t* __restrict__ P, int n)
{
  const int row = blockIdx.x;
  float* srow = S + (size_t)row * n;
  f16_t* prow = P + (size_t)row * n;
  const int t = threadIdx.x;
  const int lane = t & 63;
  const int wave = t >> 6;
  __shared__ float red[8];

  float4 v[4];
  float mx = -3.4e38f;
#pragma unroll
  for (int i = 0; i < 4; ++i) {
    v[i] = *(const float4*)(srow + (size_t)(i * 256 + t) * 4);
    mx = fmaxf(mx, fmaxf(fmaxf(v[i].x, v[i].y), fmaxf(v[i].z, v[i].w)));
  }
#pragma unroll
  for (int off = 32; off > 0; off >>= 1) mx = fmaxf(mx, __shfl_xor(mx, off));
  if (lane == 0) red[wave] = mx;
  __syncthreads();
  mx = fmaxf(fmaxf(red[0], red[1]), fmaxf(red[2], red[3]));

  float e[16];
  float sum = 0.f;
#pragma unroll
  for (int i = 0; i < 4; ++i) {
    e[4 * i + 0] = __expf(v[i].x - mx);
    e[4 * i + 1] = __expf(v[i].y - mx);
    e[4 * i + 2] = __expf(v[i].z - mx);
    e[4 * i + 3] = __expf(v[i].w - mx);
    sum += e[4 * i + 0] + e[4 * i + 1] + e[4 * i + 2] + e[4 * i + 3];
  }
#pragma unroll
  for (int off = 32; off > 0; off >>= 1) sum += __shfl_xor(sum, off);
  if (lane == 0) red[4 + wave] = sum;
  __syncthreads();
  sum = red[4] + red[5] + red[6] + red[7];
  const float inv = 1.0f / sum;

#pragma unroll
  for (int i = 0; i < 4; ++i) {
    float4 w;
    w.x = e[4 * i + 0] * inv;
    w.y = e[4 * i + 1] * inv;
    w.z = e[4 * i + 2] * inv;
    w.w = e[4 * i + 3] * inv;
    *(float4*)(srow + (size_t)(i * 256 + t) * 4) = w;
    f16x4 p;
    p[0] = (f16_t)w.x;
    p[1] = (f16_t)w.y;
    p[2] = (f16_t)w.z;
    p[3] = (f16_t)w.w;
    *(f16x4*)(prow + (size_t)(i * 256 + t) * 4) = p;
  }
}

extern "C" void kernel_launch(void* const* d_in, const int* in_sizes, int n_in,
                              void* d_out, int out_size, void* d_ws, size_t ws_size,
                              hipStream_t stream) {
  const int N = N_SEQ, D = DMODEL;
  const float* q    = (const float*)d_in[0];
  const float* k    = (const float*)d_in[1];
  const float* v    = (const float*)d_in[2];
  const float* wq_w = (const float*)d_in[3];
  const float* wq_b = (const float*)d_in[4];
  const float* wk_w = (const float*)d_in[5];
  const float* wk_b = (const float*)d_in[6];
  const float* wv_w = (const float*)d_in[7];
  const float* wv_b = (const float*)d_in[8];
  const float* wo_w = (const float*)d_in[9];
  const float* wo_b = (const float*)d_in[10];

  float* x_out = (float*)d_out;                 // [N, D]
  float* attn  = x_out + (size_t)N * D;         // [N, N]

  char* wsp = (char*)d_ws;
  auto alloc = [&](size_t bytes) { char* p = wsp; wsp += bytes; return p; };
  const size_t ND = (size_t)N * D, DD = (size_t)D * D;
  f16_t*  qh16  = (f16_t*)alloc(ND * 2);
  f16_t*  ql16  = (f16_t*)alloc(ND * 2);
  f16_t*  kh16  = (f16_t*)alloc(ND * 2);
  f16_t*  kl16  = (f16_t*)alloc(ND * 2);
  f16_t*  vh16  = (f16_t*)alloc(ND * 2);
  f16_t*  wq16  = (f16_t*)alloc(DD * 2);
  f16_t*  wk16  = (f16_t*)alloc(DD * 2);
  f16_t*  wv16  = (f16_t*)alloc(DD * 2);
  f16_t*  wo16  = (f16_t*)alloc(DD * 2);
  f16_t*  QPh   = (f16_t*)alloc(ND * 2);        // fp16 qp
  f16_t*  pad1  = (f16_t*)alloc(ND * 2);
  f16_t*  KPh   = (f16_t*)alloc(ND * 2);        // fp16 kp
  f16_t*  pad2  = (f16_t*)alloc(ND * 2);
  f16_t*  VPt   = (f16_t*)alloc(ND * 2);        // [D][N] transposed fp16
  // aliases (producers run strictly after last readers of the underlying bufs)
  f16_t*  Pb    = QPh;    // 32 MB over QPh..pad2 (dead after scores)
  f16_t*  Xb    = vh16;   // 8 MB over vh16 (dead after qkv_proj)
  (void)pad1; (void)pad2;

  // fused split: q,k -> fp16 hi+lo; v + all weights -> single fp16
  SplitDesc sd;
  sd.src[0] = q;    sd.hi[0] = qh16;  sd.lo[0] = ql16;    sd.mode[0] = 2;
  sd.src[1] = k;    sd.hi[1] = kh16;  sd.lo[1] = kl16;    sd.mode[1] = 2;
  sd.src[2] = v;    sd.hi[2] = vh16;  sd.lo[2] = nullptr; sd.mode[2] = 3;
  sd.src[3] = wq_w; sd.hi[3] = wq16;  sd.lo[3] = nullptr; sd.mode[3] = 3;
  sd.src[4] = wk_w; sd.hi[4] = wk16;  sd.lo[4] = nullptr; sd.mode[4] = 3;
  sd.src[5] = wv_w; sd.hi[5] = wv16;  sd.lo[5] = nullptr; sd.mode[5] = 3;
  sd.src[6] = wo_w; sd.hi[6] = wo16;  sd.lo[6] = nullptr; sd.mode[6] = 3;
  const int nb_nd = (int)(ND / 4 / 256);   // 4096
  const int nb_dd = (int)(DD / 4 / 256);   // 1024
  sd.blk_start[0] = 0;
  sd.blk_start[1] = nb_nd;
  sd.blk_start[2] = 2 * nb_nd;
  sd.blk_start[3] = 3 * nb_nd;
  sd.blk_start[4] = 3 * nb_nd + nb_dd;
  sd.blk_start[5] = 3 * nb_nd + 2 * nb_dd;
  sd.blk_start[6] = 3 * nb_nd + 3 * nb_dd;
  sd.blk_start[7] = 3 * nb_nd + 4 * nb_dd;
  split_all<<<dim3(sd.blk_start[7]), dim3(256), 0, stream>>>(sd);

  const dim3 blk(256);
  const dim3 gsc(N / BN, N / BM);      // (32, 32) = 1024 blocks
  const dim3 gd(D / BN2, N / BM);      // (16, 32) = 512 blocks

  // fused Q/K/V projections: Q 2-pass, K 2-pass, V 1-pass (48 KiB LDS)
  qkv_proj<<<dim3(D / BN, N / BM, 3), blk, 0, stream>>>(
      qh16, ql16, wq16, wq_b,
      kh16, kl16, wk16, wk_b,
      vh16, wv16, wv_b,
      QPh, KPh, VPt);

  // scores = QPh @ KPh^T  (128x128 pipelined, K=1024, fp32 into d_out)
  gemm_f16s<<<gsc, blk, 0, stream>>>(QPh, KPh, attn, N, N, D);

  // softmax rows in-place + fp16 copy (Pb aliases QP/KP region: dead now)
  softmax_rows<<<dim3(N), blk, 0, stream>>>(attn, Pb, N);

  // X = P @ VP  (pipelined dbuf BK=64, full K=4096 -> fp16 Xb)
  gemm_f16p<0><<<gd, blk, 0, stream>>>(
      Pb, VPt, nullptr, Xb, nullptr, N, D, N);

  // out = X @ wo^T + b  (pipelined dbuf BK=64, K=1024 -> fp32 d_out + bias)
  gemm_f16p<1><<<gd, blk, 0, stream>>>(
      Xb, wo16, wo_b, nullptr, x_out, N, D, D);
}